// Round 17
// baseline (82.394 us; speedup 1.0000x reference)
//
#include <hip/hip_runtime.h>
#include <math.h>

#define NTOK 198
#define CCH  192

typedef float vf4 __attribute__((ext_vector_type(4)));

__device__ __forceinline__ float qgelu(float v) {
    return v / (1.0f + __expf(-1.702f * v));  // x * sigmoid(1.702 x)
}

__device__ __forceinline__ float dot8(const float4& a, const float4& wa,
                                      const float4& b, const float4& wb) {
    return a.x*wa.x + a.y*wa.y + a.z*wa.z + a.w*wa.w
         + b.x*wb.x + b.y*wb.y + b.z*wb.z + b.w*wb.w;
}

// Fully fused: down-proj + qgelu -> conv3x3 + qgelu -> up-proj.
// TWO blocks per batch element (row-split, halo recomputed), 256 thr, grid 2048.
// R16 win: reg-resident w_down Phase A -> VGPR 32, occupancy 62%, 77.7us.
// R17: Phase A 2 tokens/iteration (same wreg, idx & idx+4; sub-step-interleaved
// loads) -> 29->15 iters, ~2x loads in flight, shfl bubble amortized over 2 tokens.
// Reg budget: 24 wreg + 16 buf + 4 acc + addr ~ 56 <= 64 cap of (256,4).
__global__ __launch_bounds__(256, 4) void convpass_fused(
    const float* __restrict__ x,       // [B,198,192]
    const float* __restrict__ w_down,  // [8,192]
    const float* __restrict__ b_down,  // [8]
    const float* __restrict__ conv_w,  // [8,8,3,3]
    const float* __restrict__ conv_b,  // [8]
    const float* __restrict__ w_up,    // [192,8]
    const float* __restrict__ b_up,    // [192]
    float* __restrict__ out)           // [B,198,192]
{
    const int half = blockIdx.x;       // 0: cls+dist+rows 0..6 ; 1: rows 7..13
    const int b    = blockIdx.y;
    const int tid  = threadIdx.x;

    // half 0: outputs n in [0,100), needs d tokens [0,114)
    // half 1: outputs n in [100,198), needs d tokens [86,198)
    const int d_start   = half ? 86  : 0;
    const int d_count   = half ? 112 : 114;
    const int out_start = half ? 100 : 0;
    const int out_count = half ? 98  : 100;

    __shared__ float s_d[114 * 8];    // 3648 B  down-proj out (stride 8: b128 rows)
    __shared__ float s_d2[100 * 8];   // 3200 B  conv out
    __shared__ float s_cw[576];       // 2304 B  conv weights [kk][o][i]
    __shared__ float s_cb[8];

    // ---- stage conv weights (visibility covered by the barrier after Phase A) ----
    for (int t = tid; t < 576; t += 256) {
        const int kk = t >> 6, rem = t & 63, o = rem >> 3, i = rem & 7;
        s_cw[t] = conv_w[(o * 8 + i) * 9 + kk];   // [kk][o][i] <- [o][i][kk]
    }
    if (tid < 8) s_cb[tid] = conv_b[tid];

    // ========== Phase A: d = qgelu(x @ w_down^T + b_down) -> s_d ==========
    // lane = chunk*8 + dim; w fragment in regs; TWO tokens per iteration.
    {
        const int lane  = tid & 63;
        const int wv    = tid >> 6;       // wave 0..3
        const int chunk = lane >> 3;      // 24-float c-chunk 0..7
        const int dim   = lane & 7;       // output dim 0..7

        float wreg[24];
        {
            const float* wp = w_down + dim * CCH + chunk * 24;
            #pragma unroll
            for (int j = 0; j < 24; ++j) wreg[j] = wp[j];
        }
        const float bd  = b_down[dim];
        const float* xb = x + (size_t)b * NTOK * CCH + chunk * 24;

        #pragma unroll 1
        for (int i = 0; i < 15; ++i) {
            const int idxA = i * 8 + wv;              // residues 0..3 (mod 8)
            const int idxB = idxA + 4;                // residues 4..7 (mod 8)
            const bool vA = (idxA < d_count);
            const bool vB = (idxB < d_count);
            const int nA = d_start + (vA ? idxA : 0); // safe addr for masked lanes
            const int nB = d_start + (vB ? idxB : 0);
            const float* xrA = xb + (size_t)nA * CCH;
            const float* xrB = xb + (size_t)nB * CCH;

            float a0 = 0.f, a1 = 0.f, b0 = 0.f, b1 = 0.f;
            #pragma unroll
            for (int j = 0; j < 3; ++j) {
                const float4 xa0 = *(const float4*)(xrA + j * 8);
                const float4 xa1 = *(const float4*)(xrA + j * 8 + 4);
                const float4 xb0 = *(const float4*)(xrB + j * 8);
                const float4 xb1 = *(const float4*)(xrB + j * 8 + 4);
                a0 += xa0.x*wreg[j*8]   + xa0.y*wreg[j*8+1] + xa0.z*wreg[j*8+2] + xa0.w*wreg[j*8+3];
                a1 += xa1.x*wreg[j*8+4] + xa1.y*wreg[j*8+5] + xa1.z*wreg[j*8+6] + xa1.w*wreg[j*8+7];
                b0 += xb0.x*wreg[j*8]   + xb0.y*wreg[j*8+1] + xb0.z*wreg[j*8+2] + xb0.w*wreg[j*8+3];
                b1 += xb1.x*wreg[j*8+4] + xb1.y*wreg[j*8+5] + xb1.z*wreg[j*8+6] + xb1.w*wreg[j*8+7];
            }
            float accA = a0 + a1;
            float accB = b0 + b1;
            // all-reduce over the 8 chunks (lane bits 3,4,5)
            accA += __shfl_xor(accA, 8);
            accB += __shfl_xor(accB, 8);
            accA += __shfl_xor(accA, 16);
            accB += __shfl_xor(accB, 16);
            accA += __shfl_xor(accA, 32);
            accB += __shfl_xor(accB, 32);
            if (lane < 8) {
                if (vA) s_d[idxA * 8 + dim] = qgelu(accA + bd);
                if (vB) s_d[idxB * 8 + dim] = qgelu(accB + bd);
            }
        }
    }
    __syncthreads();

    // ========== Phase B: conv3x3 + qgelu -> s_d2 (b128 reads, conflict-free) ==========
    for (int j = tid; j < out_count * 8; j += 256) {
        const int nr = j >> 3, o = j & 7;
        const int n = out_start + nr;
        if (n == 1) {
            s_d2[j] = 0.0f;            // dist token zeroed; qgelu(0)=0
        } else if (n == 0) {           // cls: center tap only (half 0: s_d idx0 = tok 0)
            const float4 d0 = *(const float4*)&s_d[0];
            const float4 d1 = *(const float4*)&s_d[4];
            const float4 w0 = *(const float4*)&s_cw[4 * 64 + o * 8];
            const float4 w1 = *(const float4*)&s_cw[4 * 64 + o * 8 + 4];
            s_d2[j] = qgelu(s_cb[o] + dot8(d0, w0, d1, w1));
        } else {
            const int pos = n - 2, h = pos / 14, w = pos % 14;
            float acc = s_cb[o];
            #pragma unroll
            for (int dh = -1; dh <= 1; ++dh) {
                const int hh = h + dh;
                if (hh < 0 || hh > 13) continue;
                #pragma unroll
                for (int dw = -1; dw <= 1; ++dw) {
                    const int ww = w + dw;
                    if (ww < 0 || ww > 13) continue;
                    const int tok = 2 + hh * 14 + ww;
                    const int kk  = (dh + 1) * 3 + (dw + 1);
                    const int ti  = tok - d_start;
                    const float4 d0 = *(const float4*)&s_d[ti * 8];
                    const float4 d1 = *(const float4*)&s_d[ti * 8 + 4];
                    const float4 w0 = *(const float4*)&s_cw[kk * 64 + o * 8];
                    const float4 w1 = *(const float4*)&s_cw[kk * 64 + o * 8 + 4];
                    acc += dot8(d0, w0, d1, w1);
                }
            }
            s_d2[j] = qgelu(acc);
        }
    }
    __syncthreads();

    // ========== Phase C: out = d2 @ w_up^T + b_up ==========
    const int c4 = tid % 48;
    const int tl = tid / 48;  // 0..5 (tl==5: 16 threads idle)
    if (tl < 5) {
        float w_r[4][8];
        #pragma unroll
        for (int cc = 0; cc < 4; ++cc) {
            const float4 wa = *(const float4*)(w_up + (c4 * 4 + cc) * 8);
            const float4 wb = *(const float4*)(w_up + (c4 * 4 + cc) * 8 + 4);
            w_r[cc][0] = wa.x; w_r[cc][1] = wa.y; w_r[cc][2] = wa.z; w_r[cc][3] = wa.w;
            w_r[cc][4] = wb.x; w_r[cc][5] = wb.y; w_r[cc][6] = wb.z; w_r[cc][7] = wb.w;
        }
        const float4 bu = *(const float4*)(b_up + c4 * 4);
        float* outb = out + ((size_t)b * NTOK + out_start) * CCH;
        #pragma unroll 1
        for (int nr = tl; nr < out_count; nr += 5) {
            const float4 da = *(const float4*)&s_d2[nr * 8];      // broadcast
            const float4 dv = *(const float4*)&s_d2[nr * 8 + 4];
            float accs[4] = {bu.x, bu.y, bu.z, bu.w};
            #pragma unroll
            for (int cc = 0; cc < 4; ++cc) {
                accs[cc] += da.x * w_r[cc][0] + da.y * w_r[cc][1]
                          + da.z * w_r[cc][2] + da.w * w_r[cc][3]
                          + dv.x * w_r[cc][4] + dv.y * w_r[cc][5]
                          + dv.z * w_r[cc][6] + dv.w * w_r[cc][7];
            }
            const vf4 r = {accs[0], accs[1], accs[2], accs[3]};
            __builtin_nontemporal_store(r, (vf4*)(outb + (size_t)nr * CCH + c4 * 4));
        }
    }
}

extern "C" void kernel_launch(void* const* d_in, const int* in_sizes, int n_in,
                              void* d_out, int out_size, void* d_ws, size_t ws_size,
                              hipStream_t stream) {
    const float* x      = (const float*)d_in[0];
    const float* w_down = (const float*)d_in[1];
    const float* b_down = (const float*)d_in[2];
    const float* conv_w = (const float*)d_in[3];
    const float* conv_b = (const float*)d_in[4];
    const float* w_up   = (const float*)d_in[5];
    const float* b_up   = (const float*)d_in[6];
    float* out = (float*)d_out;

    const int B = in_sizes[0] / (NTOK * CCH);   // 1024
    convpass_fused<<<dim3(2, B), dim3(256), 0, stream>>>(
        x, w_down, b_down, conv_w, conv_b, w_up, b_up, out);
}

// Round 18
// 76.964 us; speedup vs baseline: 1.0705x; 1.0705x over previous
//
#include <hip/hip_runtime.h>
#include <math.h>

#define NTOK 198
#define CCH  192

typedef float vf4 __attribute__((ext_vector_type(4)));

__device__ __forceinline__ float qgelu(float v) {
    return v / (1.0f + __expf(-1.702f * v));  // x * sigmoid(1.702 x)
}

__device__ __forceinline__ float dot8(const float4& a, const float4& wa,
                                      const float4& b, const float4& wb) {
    return a.x*wa.x + a.y*wa.y + a.z*wa.z + a.w*wa.w
         + b.x*wb.x + b.y*wb.y + b.z*wb.z + b.w*wb.w;
}

// Fully fused: down-proj + qgelu -> conv3x3 + qgelu -> up-proj.
// R18: ONE 512-thread block per batch element (no row-split, no halo recompute).
// Phase A = R16's reg-resident-w design (36 VGPR, 1 token/wave-iter; R17's
// 2-token variant regressed). (512,4): 64-VGPR cap, body fits -> 8 waves/SIMD,
// 4 blocks/CU = full 2048-thread residency, grid 1024 = exact one fill.
// w_up loads stay AFTER the B barrier: hoisting would push live regs past 64.
__global__ __launch_bounds__(512, 4) void convpass_fused(
    const float* __restrict__ x,       // [B,198,192]
    const float* __restrict__ w_down,  // [8,192]
    const float* __restrict__ b_down,  // [8]
    const float* __restrict__ conv_w,  // [8,8,3,3]
    const float* __restrict__ conv_b,  // [8]
    const float* __restrict__ w_up,    // [192,8]
    const float* __restrict__ b_up,    // [192]
    float* __restrict__ out)           // [B,198,192]
{
    const int b   = blockIdx.x;
    const int tid = threadIdx.x;

    __shared__ float s_d[NTOK * 8];   // 6336 B  down-proj out (stride 8: b128 rows)
    __shared__ float s_d2[NTOK * 8];  // 6336 B  conv out
    __shared__ float s_cw[576];       // 2304 B  conv weights [kk][o][i]
    __shared__ float s_cb[8];

    // ---- stage conv weights (visibility covered by the barrier after Phase A) ----
    for (int t = tid; t < 576; t += 512) {
        const int kk = t >> 6, rem = t & 63, o = rem >> 3, i = rem & 7;
        s_cw[t] = conv_w[(o * 8 + i) * 9 + kk];   // [kk][o][i] <- [o][i][kk]
    }
    if (tid < 8) s_cb[tid] = conv_b[tid];

    // ========== Phase A: d = qgelu(x @ w_down^T + b_down) -> s_d ==========
    // lane = chunk*8 + dim; w_down fragment in 24 REGISTERS; 1 token/wave-iter.
    {
        const int lane  = tid & 63;
        const int wv    = tid >> 6;       // wave 0..7
        const int chunk = lane >> 3;      // 24-float c-chunk 0..7
        const int dim   = lane & 7;       // output dim 0..7

        float wreg[24];
        {
            const float* wp = w_down + dim * CCH + chunk * 24;
            #pragma unroll
            for (int j = 0; j < 24; ++j) wreg[j] = wp[j];
        }
        const float bd  = b_down[dim];
        const float* xb = x + (size_t)b * NTOK * CCH + chunk * 24;

        #pragma unroll 1
        for (int i = 0; i < 25; ++i) {
            const int idx = i * 8 + wv;               // 0..199
            const bool valid = (idx < NTOK);
            const int n = valid ? idx : 0;            // safe addr for masked lanes
            const float* xr = xb + (size_t)n * CCH;
            // 6 independent b128 loads (8-lane broadcast groups), 2 FMA chains
            float a0 = 0.f, a1 = 0.f;
            #pragma unroll
            for (int j = 0; j < 3; ++j) {
                const float4 xv = *(const float4*)(xr + j * 8);
                const float4 xw = *(const float4*)(xr + j * 8 + 4);
                a0 += xv.x*wreg[j*8]   + xv.y*wreg[j*8+1] + xv.z*wreg[j*8+2] + xv.w*wreg[j*8+3];
                a1 += xw.x*wreg[j*8+4] + xw.y*wreg[j*8+5] + xw.z*wreg[j*8+6] + xw.w*wreg[j*8+7];
            }
            float acc = a0 + a1;
            // all-reduce over the 8 chunks (lane bits 3,4,5)
            acc += __shfl_xor(acc, 8);
            acc += __shfl_xor(acc, 16);
            acc += __shfl_xor(acc, 32);
            if (valid && lane < 8) s_d[idx * 8 + dim] = qgelu(acc + bd);
        }
    }
    __syncthreads();

    // ========== Phase B: conv3x3 + qgelu -> s_d2 (b128 reads, conflict-free) ==========
    for (int j = tid; j < NTOK * 8; j += 512) {
        const int n = j >> 3, o = j & 7;
        if (n == 1) {
            s_d2[j] = 0.0f;            // dist token zeroed; qgelu(0)=0
        } else if (n == 0) {           // cls: center tap only
            const float4 d0 = *(const float4*)&s_d[0];
            const float4 d1 = *(const float4*)&s_d[4];
            const float4 w0 = *(const float4*)&s_cw[4 * 64 + o * 8];
            const float4 w1 = *(const float4*)&s_cw[4 * 64 + o * 8 + 4];
            s_d2[j] = qgelu(s_cb[o] + dot8(d0, w0, d1, w1));
        } else {
            const int pos = n - 2, h = pos / 14, w = pos % 14;
            float acc = s_cb[o];
            #pragma unroll
            for (int dh = -1; dh <= 1; ++dh) {
                const int hh = h + dh;
                if (hh < 0 || hh > 13) continue;
                #pragma unroll
                for (int dw = -1; dw <= 1; ++dw) {
                    const int ww = w + dw;
                    if (ww < 0 || ww > 13) continue;
                    const int tok = 2 + hh * 14 + ww;
                    const int kk  = (dh + 1) * 3 + (dw + 1);
                    const float4 d0 = *(const float4*)&s_d[tok * 8];
                    const float4 d1 = *(const float4*)&s_d[tok * 8 + 4];
                    const float4 w0 = *(const float4*)&s_cw[kk * 64 + o * 8];
                    const float4 w1 = *(const float4*)&s_cw[kk * 64 + o * 8 + 4];
                    acc += dot8(d0, w0, d1, w1);
                }
            }
            s_d2[j] = qgelu(acc);
        }
    }
    __syncthreads();

    // ========== Phase C: out = d2 @ w_up^T + b_up ==========
    const int c4 = tid % 48;
    const int tl = tid / 48;  // 0..10 (tl==10: 32 threads idle)
    if (tl < 10) {
        float w_r[4][8];
        #pragma unroll
        for (int cc = 0; cc < 4; ++cc) {
            const float4 wa = *(const float4*)(w_up + (c4 * 4 + cc) * 8);
            const float4 wb = *(const float4*)(w_up + (c4 * 4 + cc) * 8 + 4);
            w_r[cc][0] = wa.x; w_r[cc][1] = wa.y; w_r[cc][2] = wa.z; w_r[cc][3] = wa.w;
            w_r[cc][4] = wb.x; w_r[cc][5] = wb.y; w_r[cc][6] = wb.z; w_r[cc][7] = wb.w;
        }
        const float4 bu = *(const float4*)(b_up + c4 * 4);
        float* outb = out + (size_t)b * NTOK * CCH;
        #pragma unroll 1
        for (int nr = tl; nr < NTOK; nr += 10) {
            const float4 da = *(const float4*)&s_d2[nr * 8];      // broadcast
            const float4 dv = *(const float4*)&s_d2[nr * 8 + 4];
            float accs[4] = {bu.x, bu.y, bu.z, bu.w};
            #pragma unroll
            for (int cc = 0; cc < 4; ++cc) {
                accs[cc] += da.x * w_r[cc][0] + da.y * w_r[cc][1]
                          + da.z * w_r[cc][2] + da.w * w_r[cc][3]
                          + dv.x * w_r[cc][4] + dv.y * w_r[cc][5]
                          + dv.z * w_r[cc][6] + dv.w * w_r[cc][7];
            }
            const vf4 r = {accs[0], accs[1], accs[2], accs[3]};
            __builtin_nontemporal_store(r, (vf4*)(outb + (size_t)nr * CCH + c4 * 4));
        }
    }
}

extern "C" void kernel_launch(void* const* d_in, const int* in_sizes, int n_in,
                              void* d_out, int out_size, void* d_ws, size_t ws_size,
                              hipStream_t stream) {
    const float* x      = (const float*)d_in[0];
    const float* w_down = (const float*)d_in[1];
    const float* b_down = (const float*)d_in[2];
    const float* conv_w = (const float*)d_in[3];
    const float* conv_b = (const float*)d_in[4];
    const float* w_up   = (const float*)d_in[5];
    const float* b_up   = (const float*)d_in[6];
    float* out = (float*)d_out;

    const int B = in_sizes[0] / (NTOK * CCH);   // 1024
    convpass_fused<<<dim3(B), dim3(512), 0, stream>>>(
        x, w_down, b_down, conv_w, conv_b, w_up, b_up, out);
}